// Round 2
// baseline (97.224 us; speedup 1.0000x reference)
//
#include <hip/hip_runtime.h>
#include <math.h>

#define NB_TOTAL 65536
#define NOBS 256
#define OUTS 773            // 2 + 514 + 257
#define PSTRIDE 16          // floats per row in ws

// Output row layout (f32):
//  [0..1]    x31
//  [2+2j]    G_s[j][0], [3+2j] G_s[j][1]   j in 0..255   -> 2..513
//  [514,515] G_o
//  [516+j]   h_s[j]                                      -> 516..771
//  [772]     h_o
//
// ws row layout (16 f32): px,py,tvs,tvc | tc,ts,ps,pp | hc,x31_0,x31_1,Go0 | Go1,ho,0,0

// ---------------------------------------------------------------------------
// K1: one thread per row — MLP + dynamics -> params in ws
// ---------------------------------------------------------------------------
__device__ __forceinline__ void mlp_dynamics(
    int row,
    const float* __restrict__ x,
    const float* __restrict__ input_mean, const float* __restrict__ input_std,
    const float* __restrict__ W1,  const float* __restrict__ b1,
    const float* __restrict__ W21, const float* __restrict__ b21,
    const float* __restrict__ W22, const float* __restrict__ b22,
    const float* __restrict__ W31, const float* __restrict__ b31,
    const float* __restrict__ W32, const float* __restrict__ b32,
    float* p /*16 floats out*/)
{
    float xr[8];
    {
        const float4 xa = *(const float4*)(x + (size_t)row * 8);
        const float4 xb = *(const float4*)(x + (size_t)row * 8 + 4);
        xr[0]=xa.x; xr[1]=xa.y; xr[2]=xa.z; xr[3]=xa.w;
        xr[4]=xb.x; xr[5]=xb.y; xr[6]=xb.z; xr[7]=xb.w;
    }

    // ---- pass 1: hid -> x21 -> x31 ----
    float acc[32];
    #pragma unroll
    for (int k = 0; k < 32; ++k) acc[k] = b21[k];

    #pragma unroll 1
    for (int i0 = 0; i0 < 128; i0 += 8) {
        float hh[8];
        #pragma unroll
        for (int u = 0; u < 8; ++u) {
            float a = b1[i0 + u];
            #pragma unroll
            for (int k = 0; k < 8; ++k)
                a = fmaf(xr[k], W1[k * 128 + i0 + u], a);
            hh[u] = fmaxf(a, 0.0f);
        }
        #pragma unroll
        for (int u = 0; u < 8; ++u) {
            #pragma unroll
            for (int k = 0; k < 32; ++k)
                acc[k] = fmaf(hh[u], W21[(i0 + u) * 32 + k], acc[k]);
        }
    }
    float x31_0 = b31[0], x31_1 = b31[1];
    #pragma unroll
    for (int k = 0; k < 32; ++k) {
        float a21 = fmaxf(acc[k], 0.0f);
        x31_0 = fmaf(a21, W31[k * 2 + 0], x31_0);
        x31_1 = fmaf(a21, W31[k * 2 + 1], x31_1);
    }

    // ---- pass 2: hid -> x22 -> x32 (recompute hid) ----
    #pragma unroll
    for (int k = 0; k < 32; ++k) acc[k] = b22[k];

    #pragma unroll 1
    for (int i0 = 0; i0 < 128; i0 += 8) {
        float hh[8];
        #pragma unroll
        for (int u = 0; u < 8; ++u) {
            float a = b1[i0 + u];
            #pragma unroll
            for (int k = 0; k < 8; ++k)
                a = fmaf(xr[k], W1[k * 128 + i0 + u], a);
            hh[u] = fmaxf(a, 0.0f);
        }
        #pragma unroll
        for (int u = 0; u < 8; ++u) {
            #pragma unroll
            for (int k = 0; k < 32; ++k)
                acc[k] = fmaf(hh[u], W22[(i0 + u) * 32 + k], acc[k]);
        }
    }
    float z0 = b32[0], z1 = b32[1];
    #pragma unroll
    for (int k = 0; k < 32; ++k) {
        float a22 = fmaxf(acc[k], 0.0f);
        z0 = fmaf(a22, W32[k * 2 + 0], z0);
        z1 = fmaf(a22, W32[k * 2 + 1], z1);
    }
    const float p0 = 4.0f / (1.0f + __expf(-z0));
    const float p1 = 4.0f / (1.0f + __expf(-z1));

    // ---- dynamics ----
    float x0v[8];
    #pragma unroll
    for (int k = 0; k < 8; ++k)
        x0v[k] = fmaf(xr[k], input_std[k], input_mean[k]);
    const float px = x0v[0], py = x0v[1], th = x0v[2], v = x0v[3];
    const float opx = x0v[4], opy = x0v[5], oth = x0v[6], ov = x0v[7];

    float st, ct, sto, cto;
    sincosf(th,  &st,  &ct);
    sincosf(oth, &sto, &cto);

    const float ps  = p0 + p1;
    const float pp  = p0 * p1;
    const float tvs = 2.0f * v * st;
    const float tvc = 2.0f * v * ct;
    const float tc  = 2.0f * ct;
    const float ts  = 2.0f * st;
    const float hc  = 2.0f * v * v;

    const float dxo = px - opx, dyo = py - opy;
    const float ob  = dxo * dxo + dyo * dyo - 1.21f;   // Ro^2 = 1.1^2
    const float rvx = v * ct - ov * cto;
    const float rvy = v * st - ov * sto;
    const float obd = 2.0f * (dxo * rvx + dyo * rvy);
    const float cth_sum = ct * cto - st * sto;          // cos(th + oth)
    const float oLf2b = 2.0f * (v * v + ov * ov - 2.0f * v * ov * cth_sum);
    const float Go0 = dxo * tvs - dyo * tvc;
    const float Go1 = -(dxo * tc + dyo * ts);
    const float ho  = oLf2b + ps * obd + pp * ob;

    p[0]=px;  p[1]=py;  p[2]=tvs; p[3]=tvc;
    p[4]=tc;  p[5]=ts;  p[6]=ps;  p[7]=pp;
    p[8]=hc;  p[9]=x31_0; p[10]=x31_1; p[11]=Go0;
    p[12]=Go1; p[13]=ho; p[14]=0.0f; p[15]=0.0f;
}

__global__ __launch_bounds__(256) void k1_mlp(
    const float* __restrict__ x,
    const float* __restrict__ input_mean, const float* __restrict__ input_std,
    const float* __restrict__ W1,  const float* __restrict__ b1,
    const float* __restrict__ W21, const float* __restrict__ b21,
    const float* __restrict__ W22, const float* __restrict__ b22,
    const float* __restrict__ W31, const float* __restrict__ b31,
    const float* __restrict__ W32, const float* __restrict__ b32,
    float* __restrict__ ws)
{
    const int row = blockIdx.x * 256 + threadIdx.x;
    float p[16];
    mlp_dynamics(row, x, input_mean, input_std,
                 W1, b1, W21, b21, W22, b22, W31, b31, W32, b32, p);
    float* wp = ws + (size_t)row * PSTRIDE;
    *(float4*)(wp + 0)  = make_float4(p[0],  p[1],  p[2],  p[3]);
    *(float4*)(wp + 4)  = make_float4(p[4],  p[5],  p[6],  p[7]);
    *(float4*)(wp + 8)  = make_float4(p[8],  p[9],  p[10], p[11]);
    *(float4*)(wp + 12) = make_float4(p[12], p[13], p[14], p[15]);
}

// ---------------------------------------------------------------------------
// K2: pure fill — one wave per row-group, dense 256B stores, 100% occupancy
// ---------------------------------------------------------------------------
__global__ __launch_bounds__(256, 8) void k2_fill(
    const float* __restrict__ obstacles,
    const float* __restrict__ ws,
    float* __restrict__ out)
{
    __shared__ float oxs[NOBS], oys[NOBS], r2s[NOBS];
    const int tid = threadIdx.x;
    {
        const float* o = obstacles + (size_t)tid * 3;
        const float a = o[0], b = o[1], r = o[2] + 0.6f;   // R = 0.5 + rad + 0.1
        oxs[tid] = a; oys[tid] = b; r2s[tid] = r * r;
    }
    __syncthreads();

    const int l = tid & 63;
    const int wslot = __builtin_amdgcn_readfirstlane(threadIdx.x) >> 6; // wave idx, SGPR
    const int wid = blockIdx.x * 4 + wslot;                            // 0..8191

    #pragma unroll 1
    for (int rr = 0; rr < 8; ++rr) {
        const int row = wid * 8 + rr;                                  // uniform
        const float* pw = ws + (size_t)row * PSTRIDE;
        const float px  = pw[0],  py    = pw[1],  tvs = pw[2],  tvc = pw[3];
        const float tc  = pw[4],  ts    = pw[5],  ps  = pw[6],  pp  = pw[7];
        const float hc  = pw[8],  x31_0 = pw[9],  x31_1 = pw[10], Go0 = pw[11];
        const float Go1 = pw[12], ho    = pw[13];

        float* rb = out + (size_t)row * OUTS;

        // G region: flat i = 0..511, i = 2j + comp. Lane-pair shares obstacle,
        // even lane writes G0, odd writes G1 -> dense 256B store per pass.
        #pragma unroll
        for (int p = 0; p < 8; ++p) {
            const int i = p * 64 + l;
            const int o = i >> 1;                 // p*32 + (l>>1): 2-way bcast
            const float dx = px - oxs[o];
            const float dy = py - oys[o];
            const float g0 = dx * tvs - dy * tvc;
            const float g1 = -(dx * tc + dy * ts);
            rb[2 + i] = (l & 1) ? g1 : g0;
        }

        // h region: dense 256B store per pass.
        #pragma unroll
        for (int p = 0; p < 4; ++p) {
            const int o = p * 64 + l;
            const float dx = px - oxs[o];
            const float dy = py - oys[o];
            const float bar  = fmaf(dx, dx, dy * dy) - r2s[o];
            const float bdot = dx * tvc + dy * tvs;
            rb[516 + o] = fmaf(ps, bdot, fmaf(pp, bar, hc));
        }

        // scalars, spread over 3 lanes
        if (l == 0)      { rb[0]   = x31_0; rb[1]   = x31_1; }
        else if (l == 1) { rb[514] = Go0;   rb[515] = Go1;   }
        else if (l == 2) { rb[772] = ho; }
    }
}

// ---------------------------------------------------------------------------
// Fallback: previous fused single kernel (used only if ws too small)
// ---------------------------------------------------------------------------
__global__ __launch_bounds__(256, 4) void fused_kernel(
    const float* __restrict__ x,
    const float* __restrict__ obstacles,
    const float* __restrict__ input_mean, const float* __restrict__ input_std,
    const float* __restrict__ W1,  const float* __restrict__ b1,
    const float* __restrict__ W21, const float* __restrict__ b21,
    const float* __restrict__ W22, const float* __restrict__ b22,
    const float* __restrict__ W31, const float* __restrict__ b31,
    const float* __restrict__ W32, const float* __restrict__ b32,
    float* __restrict__ out)
{
    __shared__ float params[64][16];
    const int tid = threadIdx.x;
    const int blockBase = blockIdx.x * 64;

    if (tid < 64) {
        const int row = blockBase + tid;
        float p[16];
        mlp_dynamics(row, x, input_mean, input_std,
                     W1, b1, W21, b21, W22, b22, W31, b31, W32, b32, p);
        float* rb = out + (size_t)row * OUTS;
        rb[0] = p[9]; rb[1] = p[10]; rb[514] = p[11]; rb[515] = p[12]; rb[772] = p[13];
        #pragma unroll
        for (int k = 0; k < 16; ++k) params[tid][k] = p[k];
    }
    __syncthreads();

    const int lane = tid & 63;
    const int wave = tid >> 6;

    float ox[4], oy[4], r2[4];
    #pragma unroll
    for (int c = 0; c < 4; ++c) {
        const float* o = obstacles + (size_t)(c * 64 + lane) * 3;
        const float a = o[0], b = o[1], r = o[2] + 0.6f;
        ox[c] = a; oy[c] = b; r2[c] = r * r;
    }

    #pragma unroll 1
    for (int rr = 0; rr < 16; ++rr) {
        const int rl = wave * 16 + rr;
        const float4 pA = *(const float4*)&params[rl][0];
        const float4 pB = *(const float4*)&params[rl][4];
        const float  hc = params[rl][8];
        const float px = pA.x, py = pA.y, tvs = pA.z, tvc = pA.w;
        const float tc = pB.x, ts = pB.y, ps  = pB.z, pp  = pB.w;

        float* rb = out + (size_t)(blockBase + rl) * OUTS;

        #pragma unroll
        for (int c = 0; c < 4; ++c) {
            const int j = c * 64 + lane;
            const float dx = px - ox[c];
            const float dy = py - oy[c];
            const float G0   = dx * tvs - dy * tvc;
            const float G1   = -(dx * tc + dy * ts);
            const float bdot = dx * tvc + dy * tvs;
            const float bar  = fmaf(dx, dx, dy * dy) - r2[c];
            const float hv   = fmaf(ps, bdot, fmaf(pp, bar, hc));
            rb[2 + 2 * j] = G0;
            rb[3 + 2 * j] = G1;
            rb[516 + j]   = hv;
        }
    }
}

extern "C" void kernel_launch(void* const* d_in, const int* in_sizes, int n_in,
                              void* d_out, int out_size, void* d_ws, size_t ws_size,
                              hipStream_t stream) {
    const float* x          = (const float*)d_in[0];
    const float* obstacles  = (const float*)d_in[1];
    const float* input_mean = (const float*)d_in[2];
    const float* input_std  = (const float*)d_in[3];
    const float* W1  = (const float*)d_in[4];
    const float* b1  = (const float*)d_in[5];
    const float* W21 = (const float*)d_in[6];
    const float* b21 = (const float*)d_in[7];
    const float* W22 = (const float*)d_in[8];
    const float* b22 = (const float*)d_in[9];
    const float* W31 = (const float*)d_in[10];
    const float* b31 = (const float*)d_in[11];
    const float* W32 = (const float*)d_in[12];
    const float* b32 = (const float*)d_in[13];

    float* out = (float*)d_out;
    const size_t ws_need = (size_t)NB_TOTAL * PSTRIDE * sizeof(float); // 4 MB

    if (ws_size >= ws_need) {
        float* ws = (float*)d_ws;
        k1_mlp<<<dim3(NB_TOTAL / 256), dim3(256), 0, stream>>>(
            x, input_mean, input_std,
            W1, b1, W21, b21, W22, b22, W31, b31, W32, b32, ws);
        k2_fill<<<dim3(NB_TOTAL / 32), dim3(256), 0, stream>>>(obstacles, ws, out);
    } else {
        fused_kernel<<<dim3(NB_TOTAL / 64), dim3(256), 0, stream>>>(
            x, obstacles, input_mean, input_std,
            W1, b1, W21, b21, W22, b22, W31, b31, W32, b32, out);
    }
}

// Round 3
// 83.788 us; speedup vs baseline: 1.1604x; 1.1604x over previous
//
#include <hip/hip_runtime.h>
#include <math.h>

#define NB_TOTAL 65536
#define NOBS 256
#define OUTS 773            // 2 + 514 + 257
#define PSTRIDE 16          // floats per row in ws

// Output row layout (f32):
//  [0..1]    x31
//  [2+2j]    G_s[j][0], [3+2j] G_s[j][1]   j in 0..255   -> 2..513
//  [514,515] G_o
//  [516+j]   h_s[j]                                      -> 516..771
//  [772]     h_o
//
// ws row layout (16 f32):
//  [0]px [1]py [2]tvs [3]tvc | [4]tc [5]ts [6]hc [7]x31_0
//  [8]x31_1 [9]Go0 [10]Go1 [11]0 | [12]ps [13]pp [14]ho [15]0

// skewed LDS index: breaks power-of-2 bank strides
#define SKW(i) ((i) + ((i) >> 4))

// ---------------------------------------------------------------------------
// K1: wave-pair per 64 rows. role0 -> x21/x31 branch + dynamics + params;
//     role1 -> x22/x32 branch + dynamics + (ps,pp,ho).
// ---------------------------------------------------------------------------
__global__ __launch_bounds__(256) void k1_mlp(
    const float* __restrict__ x,
    const float* __restrict__ input_mean, const float* __restrict__ input_std,
    const float* __restrict__ W1,  const float* __restrict__ b1,
    const float* __restrict__ W21, const float* __restrict__ b21,
    const float* __restrict__ W22, const float* __restrict__ b22,
    const float* __restrict__ W31, const float* __restrict__ b31,
    const float* __restrict__ W32, const float* __restrict__ b32,
    float* __restrict__ ws)
{
    const int gt   = blockIdx.x * 256 + threadIdx.x;     // 0..131071
    const int lane = gt & 63;
    int role = (gt >> 6) & 1;
    role = __builtin_amdgcn_readfirstlane(role);          // wave-uniform
    const int row  = ((gt >> 7) << 6) | lane;             // each row hit by both roles

    float xr[8];
    {
        const float4 xa = *(const float4*)(x + (size_t)row * 8);
        const float4 xb = *(const float4*)(x + (size_t)row * 8 + 4);
        xr[0]=xa.x; xr[1]=xa.y; xr[2]=xa.z; xr[3]=xa.w;
        xr[4]=xb.x; xr[5]=xb.y; xr[6]=xb.z; xr[7]=xb.w;
    }

    const float* Wh = role ? W22 : W21;
    const float* bh = role ? b22 : b21;
    const float* Wo = role ? W32 : W31;
    const float* bo = role ? b32 : b31;

    float acc[32];
    #pragma unroll
    for (int k = 0; k < 32; ++k) acc[k] = bh[k];

    #pragma unroll 1
    for (int i0 = 0; i0 < 128; i0 += 8) {
        float hh[8];
        #pragma unroll
        for (int u = 0; u < 8; ++u) {
            float a = b1[i0 + u];
            #pragma unroll
            for (int k = 0; k < 8; ++k)
                a = fmaf(xr[k], W1[k * 128 + i0 + u], a);
            hh[u] = fmaxf(a, 0.0f);
        }
        #pragma unroll
        for (int u = 0; u < 8; ++u) {
            #pragma unroll
            for (int k = 0; k < 32; ++k)
                acc[k] = fmaf(hh[u], Wh[(i0 + u) * 32 + k], acc[k]);
        }
    }
    float o0 = bo[0], o1 = bo[1];
    #pragma unroll
    for (int k = 0; k < 32; ++k) {
        float a = fmaxf(acc[k], 0.0f);
        o0 = fmaf(a, Wo[k * 2 + 0], o0);
        o1 = fmaf(a, Wo[k * 2 + 1], o1);
    }

    // ---- dynamics (both roles, cheap) ----
    float x0v[8];
    #pragma unroll
    for (int k = 0; k < 8; ++k)
        x0v[k] = fmaf(xr[k], input_std[k], input_mean[k]);
    const float px = x0v[0], py = x0v[1], th = x0v[2], v = x0v[3];
    const float opx = x0v[4], opy = x0v[5], oth = x0v[6], ov = x0v[7];

    float st, ct, sto, cto;
    sincosf(th,  &st,  &ct);
    sincosf(oth, &sto, &cto);

    const float tvs = 2.0f * v * st;
    const float tvc = 2.0f * v * ct;
    const float tc  = 2.0f * ct;
    const float ts  = 2.0f * st;
    const float hc  = 2.0f * v * v;

    const float dxo = px - opx, dyo = py - opy;

    float* wp = ws + (size_t)row * PSTRIDE;

    if (role == 0) {
        const float Go0 = dxo * tvs - dyo * tvc;
        const float Go1 = -(dxo * tc + dyo * ts);
        *(float4*)(wp + 0) = make_float4(px, py, tvs, tvc);
        *(float4*)(wp + 4) = make_float4(tc, ts, hc, o0);
        *(float4*)(wp + 8) = make_float4(o1, Go0, Go1, 0.0f);
    } else {
        const float p0 = 4.0f / (1.0f + __expf(-o0));
        const float p1 = 4.0f / (1.0f + __expf(-o1));
        const float ps = p0 + p1;
        const float pp = p0 * p1;
        const float ob  = dxo * dxo + dyo * dyo - 1.21f;     // Ro^2 = 1.1^2
        const float rvx = v * ct - ov * cto;
        const float rvy = v * st - ov * sto;
        const float obd = 2.0f * (dxo * rvx + dyo * rvy);
        const float cth_sum = ct * cto - st * sto;            // cos(th + oth)
        const float oLf2b = 2.0f * (v * v + ov * ov - 2.0f * v * ov * cth_sum);
        const float ho = oLf2b + ps * obd + pp * ob;
        *(float4*)(wp + 12) = make_float4(ps, pp, ho, 0.0f);
    }
}

// ---------------------------------------------------------------------------
// K2: one wave per row; row's 3092B span written as aligned 16B chunks.
// Value of each dword computed from its flat row offset f.
// ---------------------------------------------------------------------------
__global__ __launch_bounds__(256, 8) void k2_fill(
    const float* __restrict__ obstacles,
    const float* __restrict__ ws,
    float* __restrict__ out)
{
    __shared__ float oxs[SKW(255) + 1], oys[SKW(255) + 1], r2s[SKW(255) + 1];
    __shared__ float prm[16][16];

    const int tid = threadIdx.x;
    {
        const float* o = obstacles + (size_t)tid * 3;
        const float a = o[0], b = o[1], r = o[2] + 0.6f;   // R = 0.5 + rad + 0.1
        const int s = SKW(tid);
        oxs[s] = a; oys[s] = b; r2s[s] = r * r;
    }
    {
        const int rloc = tid >> 4, k = tid & 15;
        prm[rloc][k] = ws[((size_t)blockIdx.x * 16 + rloc) * PSTRIDE + k];
    }
    __syncthreads();

    const int l  = tid & 63;
    const int wv = __builtin_amdgcn_readfirstlane(tid >> 6);

    #pragma unroll 1
    for (int rr = 0; rr < 4; ++rr) {
        const int rloc = wv * 4 + rr;
        const int row  = blockIdx.x * 16 + rloc;

        const float4 pa = *(const float4*)&prm[rloc][0];   // px,py,tvs,tvc
        const float4 pb = *(const float4*)&prm[rloc][4];   // tc,ts,hc,x31_0
        const float4 pc = *(const float4*)&prm[rloc][8];   // x31_1,Go0,Go1,-
        const float4 pd = *(const float4*)&prm[rloc][12];  // ps,pp,ho,-
        const float px = pa.x, py = pa.y, tvs = pa.z, tvc = pa.w;
        const float tc = pb.x, ts = pb.y, hc  = pb.z, x31_0 = pb.w;
        const float x31_1 = pc.x, Go0 = pc.y, Go1 = pc.z;
        const float ps = pd.x, pp = pd.y, ho = pd.z;

        const unsigned base = (unsigned)row * 773u;               // dword index
        const unsigned a0   = base & ~3u;
        const unsigned nch  = (((base + 773u + 3u) & ~3u) - a0) >> 2;  // 194/195

        #pragma unroll
        for (int q = 0; q < 4; ++q) {
            const unsigned c = (unsigned)(q * 64 + l);
            if (c < nch) {
                const int f0 = (int)(a0 + 4u * c) - (int)base;    // -3..775
                float v0, v1, v2, v3;
                float vv[4];
                #pragma unroll
                for (int t = 0; t < 4; ++t) {
                    const int f = f0 + t;
                    const bool isH = (f >= 516);
                    unsigned idx = isH ? (unsigned)(f - 516)
                                       : (((unsigned)(f - 2)) >> 1);
                    if (idx > 255u) idx = 255u;
                    const int sk = SKW((int)idx);
                    const float dx = px - oxs[sk];
                    const float dy = py - oys[sk];
                    float val;
                    if (isH) {
                        const float bdot = fmaf(dx, tvc, dy * tvs);
                        const float bar  = fmaf(dx, dx, dy * dy) - r2s[sk];
                        val = fmaf(ps, bdot, fmaf(pp, bar, hc));
                    } else {
                        val = (f & 1) ? -fmaf(dx, tc, dy * ts)
                                      :  fmaf(dx, tvs, -(dy * tvc));
                    }
                    // overrides: f in {0,1} -> x31; {514,515} -> Go; 772 -> ho
                    const bool lo = ((unsigned)f < 2u);
                    const bool ov = lo | ((f >> 1) == 257);
                    const float ovA = lo ? x31_0 : Go0;
                    const float ovB = lo ? x31_1 : Go1;
                    float ovv = (f & 1) ? ovB : ovA;
                    val = ov ? ovv : val;
                    val = (f == 772) ? ho : val;
                    vv[t] = val;
                }
                v0 = vv[0]; v1 = vv[1]; v2 = vv[2]; v3 = vv[3];

                float* p = out + (a0 + 4u * c);
                if (f0 >= 0 && f0 + 3 <= 772) {
                    *(float4*)p = make_float4(v0, v1, v2, v3);     // aligned 16B
                } else if (f0 < 0) {
                    // head partial: valid t >= -f0
                    if (f0 == -1)      { p[1] = v1; *(float2*)(p + 2) = make_float2(v2, v3); }
                    else if (f0 == -2) { *(float2*)(p + 2) = make_float2(v2, v3); }
                    else               { p[3] = v3; }
                } else {
                    // tail partial: valid t <= 772 - f0
                    const int e = 772 - f0;                        // 0..2
                    if (e == 2)      { *(float2*)p = make_float2(v0, v1); p[2] = v2; }
                    else if (e == 1) { *(float2*)p = make_float2(v0, v1); }
                    else             { p[0] = v0; }
                }
            }
        }
    }
}

// ---------------------------------------------------------------------------
// Fallback: fused single kernel (used only if ws too small)
// ---------------------------------------------------------------------------
__device__ __forceinline__ void mlp_dynamics(
    int row,
    const float* __restrict__ x,
    const float* __restrict__ input_mean, const float* __restrict__ input_std,
    const float* __restrict__ W1,  const float* __restrict__ b1,
    const float* __restrict__ W21, const float* __restrict__ b21,
    const float* __restrict__ W22, const float* __restrict__ b22,
    const float* __restrict__ W31, const float* __restrict__ b31,
    const float* __restrict__ W32, const float* __restrict__ b32,
    float* p /*16 floats out*/)
{
    float xr[8];
    {
        const float4 xa = *(const float4*)(x + (size_t)row * 8);
        const float4 xb = *(const float4*)(x + (size_t)row * 8 + 4);
        xr[0]=xa.x; xr[1]=xa.y; xr[2]=xa.z; xr[3]=xa.w;
        xr[4]=xb.x; xr[5]=xb.y; xr[6]=xb.z; xr[7]=xb.w;
    }
    float acc[32];
    #pragma unroll
    for (int k = 0; k < 32; ++k) acc[k] = b21[k];
    #pragma unroll 1
    for (int i0 = 0; i0 < 128; i0 += 8) {
        float hh[8];
        #pragma unroll
        for (int u = 0; u < 8; ++u) {
            float a = b1[i0 + u];
            #pragma unroll
            for (int k = 0; k < 8; ++k)
                a = fmaf(xr[k], W1[k * 128 + i0 + u], a);
            hh[u] = fmaxf(a, 0.0f);
        }
        #pragma unroll
        for (int u = 0; u < 8; ++u)
            #pragma unroll
            for (int k = 0; k < 32; ++k)
                acc[k] = fmaf(hh[u], W21[(i0 + u) * 32 + k], acc[k]);
    }
    float x31_0 = b31[0], x31_1 = b31[1];
    #pragma unroll
    for (int k = 0; k < 32; ++k) {
        float a21 = fmaxf(acc[k], 0.0f);
        x31_0 = fmaf(a21, W31[k * 2 + 0], x31_0);
        x31_1 = fmaf(a21, W31[k * 2 + 1], x31_1);
    }
    #pragma unroll
    for (int k = 0; k < 32; ++k) acc[k] = b22[k];
    #pragma unroll 1
    for (int i0 = 0; i0 < 128; i0 += 8) {
        float hh[8];
        #pragma unroll
        for (int u = 0; u < 8; ++u) {
            float a = b1[i0 + u];
            #pragma unroll
            for (int k = 0; k < 8; ++k)
                a = fmaf(xr[k], W1[k * 128 + i0 + u], a);
            hh[u] = fmaxf(a, 0.0f);
        }
        #pragma unroll
        for (int u = 0; u < 8; ++u)
            #pragma unroll
            for (int k = 0; k < 32; ++k)
                acc[k] = fmaf(hh[u], W22[(i0 + u) * 32 + k], acc[k]);
    }
    float z0 = b32[0], z1 = b32[1];
    #pragma unroll
    for (int k = 0; k < 32; ++k) {
        float a22 = fmaxf(acc[k], 0.0f);
        z0 = fmaf(a22, W32[k * 2 + 0], z0);
        z1 = fmaf(a22, W32[k * 2 + 1], z1);
    }
    const float p0 = 4.0f / (1.0f + __expf(-z0));
    const float p1 = 4.0f / (1.0f + __expf(-z1));
    float x0v[8];
    #pragma unroll
    for (int k = 0; k < 8; ++k)
        x0v[k] = fmaf(xr[k], input_std[k], input_mean[k]);
    const float px = x0v[0], py = x0v[1], th = x0v[2], v = x0v[3];
    const float opx = x0v[4], opy = x0v[5], oth = x0v[6], ov = x0v[7];
    float st, ct, sto, cto;
    sincosf(th,  &st,  &ct);
    sincosf(oth, &sto, &cto);
    const float ps  = p0 + p1;
    const float pp  = p0 * p1;
    const float tvs = 2.0f * v * st;
    const float tvc = 2.0f * v * ct;
    const float tc  = 2.0f * ct;
    const float ts  = 2.0f * st;
    const float hc  = 2.0f * v * v;
    const float dxo = px - opx, dyo = py - opy;
    const float ob  = dxo * dxo + dyo * dyo - 1.21f;
    const float rvx = v * ct - ov * cto;
    const float rvy = v * st - ov * sto;
    const float obd = 2.0f * (dxo * rvx + dyo * rvy);
    const float cth_sum = ct * cto - st * sto;
    const float oLf2b = 2.0f * (v * v + ov * ov - 2.0f * v * ov * cth_sum);
    const float Go0 = dxo * tvs - dyo * tvc;
    const float Go1 = -(dxo * tc + dyo * ts);
    const float hov = oLf2b + ps * obd + pp * ob;
    p[0]=px;  p[1]=py;  p[2]=tvs; p[3]=tvc;
    p[4]=tc;  p[5]=ts;  p[6]=ps;  p[7]=pp;
    p[8]=hc;  p[9]=x31_0; p[10]=x31_1; p[11]=Go0;
    p[12]=Go1; p[13]=hov; p[14]=0.0f; p[15]=0.0f;
}

__global__ __launch_bounds__(256, 4) void fused_kernel(
    const float* __restrict__ x,
    const float* __restrict__ obstacles,
    const float* __restrict__ input_mean, const float* __restrict__ input_std,
    const float* __restrict__ W1,  const float* __restrict__ b1,
    const float* __restrict__ W21, const float* __restrict__ b21,
    const float* __restrict__ W22, const float* __restrict__ b22,
    const float* __restrict__ W31, const float* __restrict__ b31,
    const float* __restrict__ W32, const float* __restrict__ b32,
    float* __restrict__ out)
{
    __shared__ float params[64][16];
    const int tid = threadIdx.x;
    const int blockBase = blockIdx.x * 64;

    if (tid < 64) {
        const int row = blockBase + tid;
        float p[16];
        mlp_dynamics(row, x, input_mean, input_std,
                     W1, b1, W21, b21, W22, b22, W31, b31, W32, b32, p);
        float* rb = out + (size_t)row * OUTS;
        rb[0] = p[9]; rb[1] = p[10]; rb[514] = p[11]; rb[515] = p[12]; rb[772] = p[13];
        #pragma unroll
        for (int k = 0; k < 16; ++k) params[tid][k] = p[k];
    }
    __syncthreads();

    const int lane = tid & 63;
    const int wave = tid >> 6;
    float ox[4], oy[4], r2[4];
    #pragma unroll
    for (int c = 0; c < 4; ++c) {
        const float* o = obstacles + (size_t)(c * 64 + lane) * 3;
        const float a = o[0], b = o[1], r = o[2] + 0.6f;
        ox[c] = a; oy[c] = b; r2[c] = r * r;
    }
    #pragma unroll 1
    for (int rr = 0; rr < 16; ++rr) {
        const int rl = wave * 16 + rr;
        const float4 pA = *(const float4*)&params[rl][0];
        const float4 pB = *(const float4*)&params[rl][4];
        const float  hc = params[rl][8];
        const float px = pA.x, py = pA.y, tvs = pA.z, tvc = pA.w;
        const float tc = pB.x, ts = pB.y, ps  = pB.z, pp  = pB.w;
        float* rb = out + (size_t)(blockBase + rl) * OUTS;
        #pragma unroll
        for (int c = 0; c < 4; ++c) {
            const int j = c * 64 + lane;
            const float dx = px - ox[c];
            const float dy = py - oy[c];
            rb[2 + 2 * j] = dx * tvs - dy * tvc;
            rb[3 + 2 * j] = -(dx * tc + dy * ts);
            rb[516 + j]   = fmaf(ps, dx * tvc + dy * tvs,
                                 fmaf(pp, fmaf(dx, dx, dy * dy) - r2[c], hc));
        }
    }
}

extern "C" void kernel_launch(void* const* d_in, const int* in_sizes, int n_in,
                              void* d_out, int out_size, void* d_ws, size_t ws_size,
                              hipStream_t stream) {
    const float* x          = (const float*)d_in[0];
    const float* obstacles  = (const float*)d_in[1];
    const float* input_mean = (const float*)d_in[2];
    const float* input_std  = (const float*)d_in[3];
    const float* W1  = (const float*)d_in[4];
    const float* b1  = (const float*)d_in[5];
    const float* W21 = (const float*)d_in[6];
    const float* b21 = (const float*)d_in[7];
    const float* W22 = (const float*)d_in[8];
    const float* b22 = (const float*)d_in[9];
    const float* W31 = (const float*)d_in[10];
    const float* b31 = (const float*)d_in[11];
    const float* W32 = (const float*)d_in[12];
    const float* b32 = (const float*)d_in[13];

    float* out = (float*)d_out;
    const size_t ws_need = (size_t)NB_TOTAL * PSTRIDE * sizeof(float); // 4 MB

    if (ws_size >= ws_need) {
        float* ws = (float*)d_ws;
        k1_mlp<<<dim3(131072 / 256), dim3(256), 0, stream>>>(
            x, input_mean, input_std,
            W1, b1, W21, b21, W22, b22, W31, b31, W32, b32, ws);
        k2_fill<<<dim3(NB_TOTAL / 16), dim3(256), 0, stream>>>(obstacles, ws, out);
    } else {
        fused_kernel<<<dim3(NB_TOTAL / 64), dim3(256), 0, stream>>>(
            x, obstacles, input_mean, input_std,
            W1, b1, W21, b21, W22, b22, W31, b31, W32, b32, out);
    }
}